// Round 1
// baseline (43766.592 us; speedup 1.0000x reference)
//
#include <hip/hip_runtime.h>

// QMogrifierStack: 2-layer mogrifier LSTM, B=64 S=512 IN=512 H=1024.
// Persistent cooperative kernel: 256 blocks (1/CU), blocks 0-127 = layer 0,
// 128-255 = layer 1, pipelined (layer1 runs one time-step behind layer0).
// Weights bf16 in LDS; GEMMs via mfma_f32_16x16x32_bf16; grid barriers
// hand-rolled over a flag array in d_ws (memset to 0 each launch).

typedef __attribute__((ext_vector_type(8))) short short8;
typedef __attribute__((ext_vector_type(4))) float f32x4;

constexpr int B_ = 64, S_ = 512, IN_ = 512, H_ = 1024;
constexpr int NBLK = 256, NTHR = 256;
constexpr int WPITCH = 1032;          // padded LDS row pitch (elements)
constexpr int BH = B_ * H_;

__device__ __forceinline__ unsigned short f2bf(float f) {
  unsigned u = __builtin_bit_cast(unsigned, f);
  u += 0x7FFFu + ((u >> 16) & 1u);    // round-to-nearest-even
  return (unsigned short)(u >> 16);
}
__device__ __forceinline__ float bf2f(unsigned short h) {
  unsigned u = ((unsigned)h) << 16;
  return __builtin_bit_cast(float, u);
}
__device__ __forceinline__ float sigm(float x) { return 1.f / (1.f + __expf(-x)); }
__device__ __forceinline__ float tanh_(float x) {
  float e = __expf(2.f * x);
  return 1.f - 2.f / (e + 1.f);       // stable: ->-1 for x<<0, ->1 for x>>0
}

// Grid barrier: flag-array (one 64B-strided slot per block), monotone epochs.
__device__ __forceinline__ void gridbar(int* flags, int epoch) {
  __syncthreads();
  __threadfence();                    // make prior stores device-visible (L2 WB)
  if (threadIdx.x == 0)
    __hip_atomic_store(&flags[blockIdx.x * 16], epoch, __ATOMIC_RELEASE,
                       __HIP_MEMORY_SCOPE_AGENT);
  if (threadIdx.x < 64) {
    for (int i = (int)threadIdx.x; i < NBLK; i += 64) {
      while (__hip_atomic_load(&flags[i * 16], __ATOMIC_ACQUIRE,
                               __HIP_MEMORY_SCOPE_AGENT) < epoch) {}
    }
  }
  __syncthreads();
}

__global__ __launch_bounds__(NTHR, 1) void qmog_kernel(
    const float* __restrict__ seq, const float* __restrict__ dseq,
    const float* __restrict__ lqseq,
    const float* __restrict__ modW0, const float* __restrict__ modb0,
    const float* __restrict__ Wih0, const float* __restrict__ Whh0,
    const float* __restrict__ bih0, const float* __restrict__ bhh0,
    const float* __restrict__ modW1, const float* __restrict__ modb1,
    const float* __restrict__ Wih1, const float* __restrict__ Whh1,
    const float* __restrict__ bih1, const float* __restrict__ bhh1,
    float* __restrict__ dout, int* __restrict__ flags,
    unsigned short* __restrict__ h0r, unsigned short* __restrict__ h1r,
    unsigned short* __restrict__ u0, unsigned short* __restrict__ u1) {
  // LDS: weight slices in bf16. 32 gate rows (i,f | g,o packing) x padded K.
  __shared__ unsigned short Wih_s[32 * WPITCH];   // 66048 B
  __shared__ unsigned short Whh_s[32 * WPITCH];   // 66048 B
  __shared__ unsigned short modW_s[8 * WPITCH];   // 16512 B
  __shared__ float bias_s[32];
  __shared__ float wd_s[8], wl_s[8], mb_s[8];

  const int bid = blockIdx.x, tid = threadIdx.x;
  const int layer = bid >> 7;         // 0 or 1
  const int slice = bid & 127;        // 128 slices per layer
  const int wave = tid >> 6, lane = tid & 63;
  const int Kin = layer ? H_ : IN_;   // 1024 / 512
  const int MCB = layer ? 8 : 4;      // m-cols per block (in_l / 128)
  const int hc0 = slice * 8;          // 8 h-cols per block
  const int mc0 = slice * MCB;
  const float* modW = layer ? modW1 : modW0;
  const float* modb = layer ? modb1 : modb0;
  const float* Wih  = layer ? Wih1 : Wih0;
  const float* Whh  = layer ? Whh1 : Whh0;
  const float* bih  = layer ? bih1 : bih0;
  const float* bhh  = layer ? bhh1 : bhh0;
  unsigned short* ubuf = layer ? u1 : u0;
  unsigned short* myring = layer ? h1r : h0r;  // h ping-pong (t parity)

  // ---- one-time: stage weight slices f32->bf16 into LDS ----
  // Gate-row packing: LDS row r -> global gate row (r>>3)*H + hc0 + (r&7),
  // i.e. rows [i0..7, f0..7, g0..7, o0..7]  => N-tile0 = i|f, N-tile1 = g|o.
  for (int idx = tid; idx < 32 * Kin; idx += NTHR) {
    int row = idx / Kin, k = idx - row * Kin;
    int grow = (row >> 3) * H_ + hc0 + (row & 7);
    Wih_s[row * WPITCH + k] = f2bf(Wih[grow * Kin + k]);
  }
  for (int idx = tid; idx < 32 * H_; idx += NTHR) {
    int row = idx >> 10, k = idx & (H_ - 1);
    int grow = (row >> 3) * H_ + hc0 + (row & 7);
    Whh_s[row * WPITCH + k] = f2bf(Whh[grow * H_ + k]);
  }
  for (int idx = tid; idx < MCB * H_; idx += NTHR) {
    int row = idx >> 10, k = idx & (H_ - 1);
    modW_s[row * WPITCH + k] = f2bf(modW[(mc0 + row) * (H_ + 2) + k]);
  }
  if (tid < 32) {
    int grow = (tid >> 3) * H_ + hc0 + (tid & 7);
    bias_s[tid] = bih[grow] + bhh[grow];
  }
  if (tid < MCB) {
    wd_s[tid] = modW[(mc0 + tid) * (H_ + 2) + H_];      // d_t column
    wl_s[tid] = modW[(mc0 + tid) * (H_ + 2) + H_ + 1];  // lq_t column
    mb_s[tid] = modb[mc0 + tid];
  }
  __syncthreads();

  float creg0 = 0.f, creg1 = 0.f;     // persistent cell state (2 cells/lane)
  int epoch = 1;
  const int c = lane & 15, kg = lane >> 4;   // MFMA frag coords
  const int mt = wave;                        // M-tile (16 batches) per wave

  for (int s = 0; s <= S_; ++s) {
    const int t = layer ? (s - 1) : s;
    const bool active = (t >= 0) && (t < S_);

    if (active) {
      // ---------- phase A: m = sigmoid([h,d,lq]@modW^T + modb); u = m*x ----
      f32x4 acc = {0.f, 0.f, 0.f, 0.f};
      if (t > 0) {
        const unsigned short* hsrc =
            myring + ((t - 1) & 1) * BH + (mt * 16 + c) * H_;
        const unsigned short* brow = modW_s + (c & (MCB - 1)) * WPITCH;
#pragma unroll 4
        for (int kt = 0; kt < H_ / 32; ++kt) {
          short8 a = *(const short8*)(hsrc + kt * 32 + kg * 8);
          short8 b = *(const short8*)(brow + kt * 32 + kg * 8);
          acc = __builtin_amdgcn_mfma_f32_16x16x32_bf16(a, b, acc, 0, 0, 0);
        }
      }
      const int cm = c & (MCB - 1);
      const float wd = wd_s[cm], wl = wl_s[cm], mb = mb_s[cm];
      if (c < MCB) {
#pragma unroll
        for (int r = 0; r < 4; ++r) {
          int b_ = mt * 16 + kg * 4 + r;
          float dt = dseq[b_ * S_ + t];
          float lq = lqseq[b_ * S_ + t];
          float mval = sigm(acc[r] + dt * wd + lq * wl + mb);
          float xv = layer ? bf2f(h0r[(t & 1) * BH + b_ * H_ + mc0 + c])
                           : seq[(b_ * S_ + t) * IN_ + mc0 + c];
          ubuf[b_ * Kin + mc0 + c] = f2bf(mval * xv);
        }
      }
    }
    gridbar(flags, epoch++);

    if (active) {
      // ---------- phase B: gates = u@Wih^T + h@Whh^T + b; LSTM cell --------
      f32x4 g0 = {0.f, 0.f, 0.f, 0.f}, g1 = {0.f, 0.f, 0.f, 0.f};
      {
        const unsigned short* arow = ubuf + (mt * 16 + c) * Kin;
        const unsigned short* b0 = Wih_s + c * WPITCH;
        const unsigned short* b1 = Wih_s + (16 + c) * WPITCH;
#pragma unroll 4
        for (int kt = 0; kt < Kin / 32; ++kt) {
          short8 a = *(const short8*)(arow + kt * 32 + kg * 8);
          short8 w0 = *(const short8*)(b0 + kt * 32 + kg * 8);
          short8 w1 = *(const short8*)(b1 + kt * 32 + kg * 8);
          g0 = __builtin_amdgcn_mfma_f32_16x16x32_bf16(a, w0, g0, 0, 0, 0);
          g1 = __builtin_amdgcn_mfma_f32_16x16x32_bf16(a, w1, g1, 0, 0, 0);
        }
      }
      if (t > 0) {
        const unsigned short* arow =
            myring + ((t - 1) & 1) * BH + (mt * 16 + c) * H_;
        const unsigned short* b0 = Whh_s + c * WPITCH;
        const unsigned short* b1 = Whh_s + (16 + c) * WPITCH;
#pragma unroll 4
        for (int kt = 0; kt < H_ / 32; ++kt) {
          short8 a = *(const short8*)(arow + kt * 32 + kg * 8);
          short8 w0 = *(const short8*)(b0 + kt * 32 + kg * 8);
          short8 w1 = *(const short8*)(b1 + kt * 32 + kg * 8);
          g0 = __builtin_amdgcn_mfma_f32_16x16x32_bf16(a, w0, g0, 0, 0, 0);
          g1 = __builtin_amdgcn_mfma_f32_16x16x32_bf16(a, w1, g1, 0, 0, 0);
        }
      }
      const float bia0 = bias_s[c], bia1 = bias_s[16 + c];
      f32x4 s0, s1;
#pragma unroll
      for (int r = 0; r < 4; ++r) { g0[r] += bia0; g1[r] += bia1; }
#pragma unroll
      for (int r = 0; r < 4; ++r) {
        s0[r] = __shfl_xor(g0[r], 8);
        s1[r] = __shfl_xor(g1[r], 8);
      }
      // Lane c<8 holds i (tile0) / g (tile1); lane c>=8 holds f / o.
      // After xor-8 every lane has all four; low lanes take acc rows 0,1,
      // high lanes rows 2,3 (no duplication; 2 cells per lane).
      const bool low = c < 8;
      const int hc = hc0 + (c & 7);
      const int rbase = low ? 0 : 2;
#pragma unroll
      for (int j = 0; j < 2; ++j) {
        const int rr = rbase + j;
        float iv = low ? g0[rr] : s0[rr];
        float fv = low ? s0[rr] : g0[rr];
        float gv = low ? g1[rr] : s1[rr];
        float ov = low ? s1[rr] : g1[rr];
        float cold = j ? creg1 : creg0;
        float cn = sigm(fv) * cold + sigm(iv) * tanh_(gv);
        float hn = sigm(ov) * tanh_(cn);
        if (j) creg1 = cn; else creg0 = cn;
        int b_ = mt * 16 + kg * 4 + rr;
        myring[(t & 1) * BH + b_ * H_ + hc] = f2bf(hn);
        if (layer) {
          dout[(b_ * S_ + t) * H_ + hc] = hn;
          if (t == S_ - 1) dout[B_ * S_ * H_ + b_ * H_ + hc] = hn;
        }
      }
    }
    gridbar(flags, epoch++);
  }
}

extern "C" void kernel_launch(void* const* d_in, const int* in_sizes, int n_in,
                              void* d_out, int out_size, void* d_ws,
                              size_t ws_size, hipStream_t stream) {
  char* w = (char*)d_ws;
  int* flags = (int*)w;                                          // 16 KB
  unsigned short* h0r = (unsigned short*)(w + 16384);            // 256 KB
  unsigned short* h1r = (unsigned short*)(w + 16384 + 262144);   // 256 KB
  unsigned short* u0 = (unsigned short*)(w + 16384 + 2 * 262144);          // 64 KB
  unsigned short* u1 = (unsigned short*)(w + 16384 + 2 * 262144 + 65536);  // 128 KB

  hipMemsetAsync(flags, 0, 16384, stream);  // epochs restart each launch

  qmog_kernel<<<NBLK, NTHR, 0, stream>>>(
      (const float*)d_in[0], (const float*)d_in[1], (const float*)d_in[2],
      (const float*)d_in[3], (const float*)d_in[4], (const float*)d_in[5],
      (const float*)d_in[6], (const float*)d_in[7], (const float*)d_in[8],
      (const float*)d_in[9], (const float*)d_in[10], (const float*)d_in[11],
      (const float*)d_in[12], (const float*)d_in[13], (const float*)d_in[14],
      (float*)d_out, flags, h0r, h1r, u0, u1);
}

// Round 2
// 15691.714 us; speedup vs baseline: 2.7892x; 2.7892x over previous
//
#include <hip/hip_runtime.h>

// QMogrifierStack: 2-layer mogrifier LSTM, B=64 S=512 IN=512 H=1024.
// Persistent cooperative kernel: 256 blocks (1/CU), blocks 0-127 = layer 0,
// 128-255 = layer 1, pipelined (layer1 runs one time-step behind layer0).
// Weights bf16 in LDS; GEMMs via mfma_f32_16x16x32_bf16.
// Cross-XCD communication: h/u written with sc0|sc1 write-through stores
// (straight to coherence point / L3, L2 stays clean), grid barrier uses
// RELAXED agent flag ops (no per-iteration cache ops) + ONE buffer_inv sc1
// per block per barrier so cached readers refetch fresh lines.

typedef __attribute__((ext_vector_type(8))) short short8;
typedef __attribute__((ext_vector_type(4))) float f32x4;

constexpr int B_ = 64, S_ = 512, IN_ = 512, H_ = 1024;
constexpr int NBLK = 256, NTHR = 256;
constexpr int WPITCH = 1032;          // padded LDS row pitch (elements)
constexpr int BH = B_ * H_;

__device__ __forceinline__ unsigned short f2bf(float f) {
  unsigned u = __builtin_bit_cast(unsigned, f);
  u += 0x7FFFu + ((u >> 16) & 1u);    // round-to-nearest-even
  return (unsigned short)(u >> 16);
}
__device__ __forceinline__ float bf2f(unsigned short h) {
  unsigned u = ((unsigned)h) << 16;
  return __builtin_bit_cast(float, u);
}
__device__ __forceinline__ float sigm(float x) { return 1.f / (1.f + __expf(-x)); }
__device__ __forceinline__ float tanh_(float x) {
  float e = __expf(2.f * x);
  return 1.f - 2.f / (e + 1.f);       // stable: ->-1 for x<<0, ->1 for x>>0
}

// Write-through store to the device coherence point (visible cross-XCD after
// s_waitcnt vmcnt(0); this is what relaxed agent atomic stores lower to).
__device__ __forceinline__ void store_short_wt(unsigned short* p, unsigned short v) {
  unsigned w = v;
  asm volatile("global_store_short %0, %1, off sc0 sc1" :: "v"(p), "v"(w) : "memory");
}

// Grid barrier. Protocol:
//  arrive: [own sc1 stores] -> s_waitcnt vmcnt(0) -> __syncthreads
//          -> tid0: relaxed agent flag store (sc1)
//  wait:   wave0 spins on 256 packed flags with RELAXED agent loads (4/lane)
//  exit:   wave0: one buffer_inv sc1 (drop stale clean L2/L1 lines) -> barrier
__device__ __forceinline__ void gridbar(int* flags, int epoch) {
  asm volatile("s_waitcnt vmcnt(0)" ::: "memory");
  __syncthreads();
  if (threadIdx.x == 0)
    __hip_atomic_store(&flags[blockIdx.x], epoch, __ATOMIC_RELAXED,
                       __HIP_MEMORY_SCOPE_AGENT);
  if (threadIdx.x < 64) {
    bool ok;
    do {
      ok = true;
#pragma unroll
      for (int i = 0; i < 4; ++i) {
        int f = __hip_atomic_load(&flags[threadIdx.x + i * 64], __ATOMIC_RELAXED,
                                  __HIP_MEMORY_SCOPE_AGENT);
        ok &= (f >= epoch);
      }
    } while (!__all(ok));
    asm volatile("buffer_inv sc1\n\ts_waitcnt vmcnt(0)" ::: "memory");
  }
  __syncthreads();
}

__global__ __launch_bounds__(NTHR, 1) void qmog_kernel(
    const float* __restrict__ seq, const float* __restrict__ dseq,
    const float* __restrict__ lqseq,
    const float* __restrict__ modW0, const float* __restrict__ modb0,
    const float* __restrict__ Wih0, const float* __restrict__ Whh0,
    const float* __restrict__ bih0, const float* __restrict__ bhh0,
    const float* __restrict__ modW1, const float* __restrict__ modb1,
    const float* __restrict__ Wih1, const float* __restrict__ Whh1,
    const float* __restrict__ bih1, const float* __restrict__ bhh1,
    float* __restrict__ dout, int* __restrict__ flags,
    unsigned short* __restrict__ h0r, unsigned short* __restrict__ h1r,
    unsigned short* __restrict__ u0, unsigned short* __restrict__ u1) {
  // LDS: weight slices in bf16. 32 gate rows (i,f | g,o packing) x padded K.
  __shared__ unsigned short Wih_s[32 * WPITCH];   // 66048 B
  __shared__ unsigned short Whh_s[32 * WPITCH];   // 66048 B
  __shared__ unsigned short modW_s[8 * WPITCH];   // 16512 B
  __shared__ float bias_s[32];
  __shared__ float wd_s[8], wl_s[8], mb_s[8];

  const int bid = blockIdx.x, tid = threadIdx.x;
  const int layer = bid >> 7;         // 0 or 1
  const int slice = bid & 127;        // 128 slices per layer
  const int wave = tid >> 6, lane = tid & 63;
  const int Kin = layer ? H_ : IN_;   // 1024 / 512
  const int MCB = layer ? 8 : 4;      // m-cols per block (in_l / 128)
  const int hc0 = slice * 8;          // 8 h-cols per block
  const int mc0 = slice * MCB;
  const float* modW = layer ? modW1 : modW0;
  const float* modb = layer ? modb1 : modb0;
  const float* Wih  = layer ? Wih1 : Wih0;
  const float* Whh  = layer ? Whh1 : Whh0;
  const float* bih  = layer ? bih1 : bih0;
  const float* bhh  = layer ? bhh1 : bhh0;
  unsigned short* ubuf = layer ? u1 : u0;
  unsigned short* myring = layer ? h1r : h0r;  // h ping-pong (t parity)

  // ---- one-time: stage weight slices f32->bf16 into LDS ----
  // Gate-row packing: LDS row r -> global gate row (r>>3)*H + hc0 + (r&7),
  // i.e. rows [i0..7, f0..7, g0..7, o0..7]  => N-tile0 = i|f, N-tile1 = g|o.
  for (int idx = tid; idx < 32 * Kin; idx += NTHR) {
    int row = idx / Kin, k = idx - row * Kin;
    int grow = (row >> 3) * H_ + hc0 + (row & 7);
    Wih_s[row * WPITCH + k] = f2bf(Wih[grow * Kin + k]);
  }
  for (int idx = tid; idx < 32 * H_; idx += NTHR) {
    int row = idx >> 10, k = idx & (H_ - 1);
    int grow = (row >> 3) * H_ + hc0 + (row & 7);
    Whh_s[row * WPITCH + k] = f2bf(Whh[grow * H_ + k]);
  }
  for (int idx = tid; idx < MCB * H_; idx += NTHR) {
    int row = idx >> 10, k = idx & (H_ - 1);
    modW_s[row * WPITCH + k] = f2bf(modW[(mc0 + row) * (H_ + 2) + k]);
  }
  if (tid < 32) {
    int grow = (tid >> 3) * H_ + hc0 + (tid & 7);
    bias_s[tid] = bih[grow] + bhh[grow];
  }
  if (tid < MCB) {
    wd_s[tid] = modW[(mc0 + tid) * (H_ + 2) + H_];      // d_t column
    wl_s[tid] = modW[(mc0 + tid) * (H_ + 2) + H_ + 1];  // lq_t column
    mb_s[tid] = modb[mc0 + tid];
  }
  __syncthreads();

  float creg0 = 0.f, creg1 = 0.f;     // persistent cell state (2 cells/lane)
  int epoch = 1;
  const int c = lane & 15, kg = lane >> 4;   // MFMA frag coords
  const int mt = wave;                        // M-tile (16 batches) per wave

  for (int s = 0; s <= S_; ++s) {
    const int t = layer ? (s - 1) : s;
    const bool active = (t >= 0) && (t < S_);

    if (active) {
      // ---------- phase A: m = sigmoid([h,d,lq]@modW^T + modb); u = m*x ----
      f32x4 aa = {0.f, 0.f, 0.f, 0.f}, ab = {0.f, 0.f, 0.f, 0.f};
      if (t > 0) {
        const unsigned short* hsrc =
            myring + ((t - 1) & 1) * BH + (mt * 16 + c) * H_;
        const unsigned short* brow = modW_s + (c & (MCB - 1)) * WPITCH;
#pragma unroll 4
        for (int kt = 0; kt < H_ / 32; kt += 2) {
          short8 a0 = *(const short8*)(hsrc + kt * 32 + kg * 8);
          short8 b0 = *(const short8*)(brow + kt * 32 + kg * 8);
          short8 a1 = *(const short8*)(hsrc + (kt + 1) * 32 + kg * 8);
          short8 b1 = *(const short8*)(brow + (kt + 1) * 32 + kg * 8);
          aa = __builtin_amdgcn_mfma_f32_16x16x32_bf16(a0, b0, aa, 0, 0, 0);
          ab = __builtin_amdgcn_mfma_f32_16x16x32_bf16(a1, b1, ab, 0, 0, 0);
        }
      }
      const int cm = c & (MCB - 1);
      const float wd = wd_s[cm], wl = wl_s[cm], mb = mb_s[cm];
      if (c < MCB) {
#pragma unroll
        for (int r = 0; r < 4; ++r) {
          int b_ = mt * 16 + kg * 4 + r;
          float dt = dseq[b_ * S_ + t];
          float lq = lqseq[b_ * S_ + t];
          float mval = sigm(aa[r] + ab[r] + dt * wd + lq * wl + mb);
          float xv = layer ? bf2f(h0r[(t & 1) * BH + b_ * H_ + mc0 + c])
                           : seq[(b_ * S_ + t) * IN_ + mc0 + c];
          store_short_wt(&ubuf[b_ * Kin + mc0 + c], f2bf(mval * xv));
        }
      }
    }
    gridbar(flags, epoch++);

    if (active) {
      // ---------- phase B: gates = u@Wih^T + h@Whh^T + b; LSTM cell --------
      // Fused K-loops: 4 independent MFMA chains (g0,g1,p0,p1) for ILP.
      f32x4 g0 = {0.f, 0.f, 0.f, 0.f}, g1 = {0.f, 0.f, 0.f, 0.f};
      f32x4 p0 = {0.f, 0.f, 0.f, 0.f}, p1 = {0.f, 0.f, 0.f, 0.f};
      const int KU = Kin / 32;        // 16 (L0) or 32 (L1)
      const unsigned short* urow = ubuf + (mt * 16 + c) * Kin;
      const unsigned short* wb0 = Wih_s + c * WPITCH;
      const unsigned short* wb1 = Wih_s + (16 + c) * WPITCH;
      const unsigned short* hrow =
          myring + ((t - 1) & 1) * BH + (mt * 16 + c) * H_;
      const unsigned short* hb0 = Whh_s + c * WPITCH;
      const unsigned short* hb1 = Whh_s + (16 + c) * WPITCH;
      if (t > 0) {
#pragma unroll 4
        for (int kt = 0; kt < 32; ++kt) {
          short8 ah = *(const short8*)(hrow + kt * 32 + kg * 8);
          short8 w0 = *(const short8*)(hb0 + kt * 32 + kg * 8);
          short8 w1 = *(const short8*)(hb1 + kt * 32 + kg * 8);
          p0 = __builtin_amdgcn_mfma_f32_16x16x32_bf16(ah, w0, p0, 0, 0, 0);
          p1 = __builtin_amdgcn_mfma_f32_16x16x32_bf16(ah, w1, p1, 0, 0, 0);
          if (kt < KU) {
            short8 au = *(const short8*)(urow + kt * 32 + kg * 8);
            short8 v0 = *(const short8*)(wb0 + kt * 32 + kg * 8);
            short8 v1 = *(const short8*)(wb1 + kt * 32 + kg * 8);
            g0 = __builtin_amdgcn_mfma_f32_16x16x32_bf16(au, v0, g0, 0, 0, 0);
            g1 = __builtin_amdgcn_mfma_f32_16x16x32_bf16(au, v1, g1, 0, 0, 0);
          }
        }
      } else {
#pragma unroll 4
        for (int kt = 0; kt < KU; ++kt) {
          short8 au = *(const short8*)(urow + kt * 32 + kg * 8);
          short8 v0 = *(const short8*)(wb0 + kt * 32 + kg * 8);
          short8 v1 = *(const short8*)(wb1 + kt * 32 + kg * 8);
          g0 = __builtin_amdgcn_mfma_f32_16x16x32_bf16(au, v0, g0, 0, 0, 0);
          g1 = __builtin_amdgcn_mfma_f32_16x16x32_bf16(au, v1, g1, 0, 0, 0);
        }
      }
      const float bia0 = bias_s[c], bia1 = bias_s[16 + c];
      f32x4 s0, s1;
#pragma unroll
      for (int r = 0; r < 4; ++r) {
        g0[r] += p0[r] + bia0;
        g1[r] += p1[r] + bia1;
      }
#pragma unroll
      for (int r = 0; r < 4; ++r) {
        s0[r] = __shfl_xor(g0[r], 8);
        s1[r] = __shfl_xor(g1[r], 8);
      }
      // Lane c<8 holds i (tile0) / g (tile1); lane c>=8 holds f / o.
      // After xor-8 every lane has all four; low lanes take acc rows 0,1,
      // high lanes rows 2,3 (no duplication; 2 cells per lane).
      const bool low = c < 8;
      const int hc = hc0 + (c & 7);
      const int rbase = low ? 0 : 2;
#pragma unroll
      for (int j = 0; j < 2; ++j) {
        const int rr = rbase + j;
        float iv = low ? g0[rr] : s0[rr];
        float fv = low ? s0[rr] : g0[rr];
        float gv = low ? g1[rr] : s1[rr];
        float ov = low ? s1[rr] : g1[rr];
        float cold = j ? creg1 : creg0;
        float cn = sigm(fv) * cold + sigm(iv) * tanh_(gv);
        float hn = sigm(ov) * tanh_(cn);
        if (j) creg1 = cn; else creg0 = cn;
        int b_ = mt * 16 + kg * 4 + rr;
        store_short_wt(&myring[(t & 1) * BH + b_ * H_ + hc], f2bf(hn));
        if (layer) {
          dout[(b_ * S_ + t) * H_ + hc] = hn;
          if (t == S_ - 1) dout[B_ * S_ * H_ + b_ * H_ + hc] = hn;
        }
      }
    }
    gridbar(flags, epoch++);
  }
}

extern "C" void kernel_launch(void* const* d_in, const int* in_sizes, int n_in,
                              void* d_out, int out_size, void* d_ws,
                              size_t ws_size, hipStream_t stream) {
  char* w = (char*)d_ws;
  int* flags = (int*)w;                                          // 1 KB used
  unsigned short* h0r = (unsigned short*)(w + 16384);            // 256 KB
  unsigned short* h1r = (unsigned short*)(w + 16384 + 262144);   // 256 KB
  unsigned short* u0 = (unsigned short*)(w + 16384 + 2 * 262144);          // 64 KB
  unsigned short* u1 = (unsigned short*)(w + 16384 + 2 * 262144 + 65536);  // 128 KB

  hipMemsetAsync(flags, 0, 16384, stream);  // epochs restart each launch

  qmog_kernel<<<NBLK, NTHR, 0, stream>>>(
      (const float*)d_in[0], (const float*)d_in[1], (const float*)d_in[2],
      (const float*)d_in[3], (const float*)d_in[4], (const float*)d_in[5],
      (const float*)d_in[6], (const float*)d_in[7], (const float*)d_in[8],
      (const float*)d_in[9], (const float*)d_in[10], (const float*)d_in[11],
      (const float*)d_in[12], (const float*)d_in[13], (const float*)d_in[14],
      (float*)d_out, flags, h0r, h1r, u0, u1);
}

// Round 3
// 12421.494 us; speedup vs baseline: 3.5235x; 1.2633x over previous
//
#include <hip/hip_runtime.h>

// QMogrifierStack: 2-layer mogrifier LSTM, B=64 S=512 IN=512 H=1024.
// Persistent cooperative kernel: 256 blocks (1/CU), blocks 0-127 = layer 0,
// 128-255 = layer 1, pipelined (layer1 one step behind layer0).
// Cross-block data: WT stores (sc0 sc1) + agent-relaxed atomic loads (sc1,
// L2-bypass) => no cache invalidates needed anywhere.
// Grid barrier: master (block 0) polls 256 arrive flags, publishes 8 go slots;
// workers spin on one go line each.

typedef __attribute__((ext_vector_type(8))) short short8;
typedef __attribute__((ext_vector_type(4))) float f32x4;
typedef unsigned long long u64;
typedef __attribute__((ext_vector_type(2))) unsigned long long u64x2;

constexpr int B_ = 64, S_ = 512, IN_ = 512, H_ = 1024;
constexpr int NBLK = 256, NTHR = 256;
constexpr int BH = B_ * H_;

__device__ __forceinline__ unsigned short f2bf(float f) {
  unsigned u = __builtin_bit_cast(unsigned, f);
  u += 0x7FFFu + ((u >> 16) & 1u);
  return (unsigned short)(u >> 16);
}
__device__ __forceinline__ float bf2f(unsigned short h) {
  unsigned u = ((unsigned)h) << 16;
  return __builtin_bit_cast(float, u);
}
__device__ __forceinline__ float sigm(float x) { return 1.f / (1.f + __expf(-x)); }
__device__ __forceinline__ float tanh_(float x) {
  float e = __expf(2.f * x);
  return 1.f - 2.f / (e + 1.f);
}

// Write-through store (visible at coherence point after vmcnt(0)).
__device__ __forceinline__ void store_short_wt(unsigned short* p, unsigned short v) {
  unsigned w = v;
  asm volatile("global_store_short %0, %1, off sc0 sc1" :: "v"(p), "v"(w) : "memory");
}

// L2-bypassing 16B load (two 8B agent-relaxed atomic loads; compiler-managed
// waitcnt/scheduling). Always reads fresh data from the coherence point.
__device__ __forceinline__ short8 load_a16(const unsigned short* p) {
  u64 lo = __hip_atomic_load((const u64*)p, __ATOMIC_RELAXED, __HIP_MEMORY_SCOPE_AGENT);
  u64 hi = __hip_atomic_load((const u64*)p + 1, __ATOMIC_RELAXED, __HIP_MEMORY_SCOPE_AGENT);
  u64x2 t; t[0] = lo; t[1] = hi;
  return __builtin_bit_cast(short8, t);
}
__device__ __forceinline__ unsigned load_a4(const unsigned short* p) {
  return __hip_atomic_load((const unsigned*)p, __ATOMIC_RELAXED, __HIP_MEMORY_SCOPE_AGENT);
}

// LDS swizzled offset: pitch 1024 elems/row, 16B-block index XOR row&7.
__device__ __forceinline__ int swoff(int row, int k) {
  return row * 1024 + ((((k >> 3) ^ (row & 7)) << 3) | (k & 7));
}

// flags[0..255] arrive; flags[256 + 32*i], i<8: replicated go slots.
__device__ __forceinline__ void gridbar(int* flags, int epoch) {
  asm volatile("s_waitcnt vmcnt(0)" ::: "memory");
  __syncthreads();
  const int tid = threadIdx.x;
  if (tid == 0)
    __hip_atomic_store(&flags[blockIdx.x], epoch, __ATOMIC_RELAXED,
                       __HIP_MEMORY_SCOPE_AGENT);
  if (blockIdx.x == 0) {
    if (tid < 64) {
      bool ok;
      do {
        ok = true;
#pragma unroll
        for (int i = 0; i < 4; ++i)
          ok &= (__hip_atomic_load(&flags[tid + i * 64], __ATOMIC_RELAXED,
                                   __HIP_MEMORY_SCOPE_AGENT) >= epoch);
      } while (!__all(ok));
      if (tid < 8)
        __hip_atomic_store(&flags[256 + (tid << 5)], epoch, __ATOMIC_RELAXED,
                           __HIP_MEMORY_SCOPE_AGENT);
    }
  } else if (tid == 0) {
    while (__hip_atomic_load(&flags[256 + ((blockIdx.x & 7) << 5)],
                             __ATOMIC_RELAXED, __HIP_MEMORY_SCOPE_AGENT) < epoch) {}
  }
  __syncthreads();
}

__global__ __launch_bounds__(NTHR, 1) void qmog_kernel(
    const float* __restrict__ seq, const float* __restrict__ dseq,
    const float* __restrict__ lqseq,
    const float* __restrict__ modW0, const float* __restrict__ modb0,
    const float* __restrict__ Wih0, const float* __restrict__ Whh0,
    const float* __restrict__ bih0, const float* __restrict__ bhh0,
    const float* __restrict__ modW1, const float* __restrict__ modb1,
    const float* __restrict__ Wih1, const float* __restrict__ Whh1,
    const float* __restrict__ bih1, const float* __restrict__ bhh1,
    float* __restrict__ dout, int* __restrict__ flags,
    unsigned short* __restrict__ h0r, unsigned short* __restrict__ h1r,
    unsigned short* __restrict__ u0, unsigned short* __restrict__ u1) {
  __shared__ unsigned short Wih_s[32 * 1024];   // 64 KB
  __shared__ unsigned short Whh_s[32 * 1024];   // 64 KB
  __shared__ unsigned short modW_s[8 * 1024];   // 16 KB
  __shared__ float bias_s[32];
  __shared__ float wd_s[8], wl_s[8], mb_s[8];

  const int bid = blockIdx.x, tid = threadIdx.x;
  const int layer = bid >> 7;
  const int slice = bid & 127;
  const int wave = tid >> 6, lane = tid & 63;
  const int Kin = layer ? H_ : IN_;   // 1024 / 512
  const int KU = Kin / 32;            // 32 / 16
  const int MCB = layer ? 8 : 4;      // m-cols per block
  const int hc0 = slice * 8;
  const int mc0 = slice * MCB;
  const float* modW = layer ? modW1 : modW0;
  const float* modb = layer ? modb1 : modb0;
  const float* Wih  = layer ? Wih1 : Wih0;
  const float* Whh  = layer ? Whh1 : Whh0;
  const float* bih  = layer ? bih1 : bih0;
  const float* bhh  = layer ? bhh1 : bhh0;
  unsigned short* ubuf = layer ? u1 : u0;
  unsigned short* myring = layer ? h1r : h0r;

  // ---- stage weight slices f32->bf16 into swizzled LDS ----
  // LDS row r -> global gate row (r>>3)*H + hc0 + (r&7): [i0..7,f0..7,g0..7,o0..7]
  for (int idx = tid; idx < 32 * Kin; idx += NTHR) {
    int row = idx / Kin, k = idx - row * Kin;
    int grow = (row >> 3) * H_ + hc0 + (row & 7);
    Wih_s[swoff(row, k)] = f2bf(Wih[grow * Kin + k]);
  }
  for (int idx = tid; idx < 32 * H_; idx += NTHR) {
    int row = idx >> 10, k = idx & (H_ - 1);
    int grow = (row >> 3) * H_ + hc0 + (row & 7);
    Whh_s[swoff(row, k)] = f2bf(Whh[grow * H_ + k]);
  }
  for (int idx = tid; idx < MCB * H_; idx += NTHR) {
    int row = idx >> 10, k = idx & (H_ - 1);
    modW_s[swoff(row, k)] = f2bf(modW[(mc0 + row) * (H_ + 2) + k]);
  }
  if (tid < 32) {
    int grow = (tid >> 3) * H_ + hc0 + (tid & 7);
    bias_s[tid] = bih[grow] + bhh[grow];
  }
  if (tid < MCB) {
    wd_s[tid] = modW[(mc0 + tid) * (H_ + 2) + H_];
    wl_s[tid] = modW[(mc0 + tid) * (H_ + 2) + H_ + 1];
    mb_s[tid] = modb[mc0 + tid];
  }
  __syncthreads();

  float creg0 = 0.f, creg1 = 0.f;
  int epoch = 1;
  const int c = lane & 15, kg = lane >> 4;
  const int mt = wave;
  const int cm = c & (MCB - 1);
  const int xr = c & 7;

  for (int s = 0; s <= S_; ++s) {
    const int t = layer ? (s - 1) : s;
    const bool active = (t >= 0) && (t < S_);

    // p-accumulators (h@Whh^T) carried across barrier1
    f32x4 p0a = {0,0,0,0}, p0b = {0,0,0,0}, p1a = {0,0,0,0}, p1b = {0,0,0,0};

    if (active) {
      // ---- phase 1: mod-GEMM + Whh-GEMM (one h read feeds 3 chains) ----
      f32x4 aa = {0,0,0,0}, ab = {0,0,0,0};
      if (t > 0) {
        const unsigned short* hrow =
            myring + ((t - 1) & 1) * BH + (mt * 16 + c) * H_;
        const unsigned short* wm = modW_s + cm * 1024;
        const unsigned short* w0b = Whh_s + c * 1024;
        const unsigned short* w1b = Whh_s + (16 + c) * 1024;
#pragma unroll 4
        for (int kt = 0; kt < 32; ++kt) {
          short8 ha = load_a16(hrow + kt * 32 + kg * 8);
          int blk = kt * 4 + kg;
          int so = ((blk ^ xr) << 3);
          int som = ((blk ^ cm) << 3);
          short8 bm = *(const short8*)(wm + som);
          short8 w0 = *(const short8*)(w0b + so);
          short8 w1 = *(const short8*)(w1b + so);
          if (kt & 1) {
            ab = __builtin_amdgcn_mfma_f32_16x16x32_bf16(ha, bm, ab, 0, 0, 0);
            p0b = __builtin_amdgcn_mfma_f32_16x16x32_bf16(ha, w0, p0b, 0, 0, 0);
            p1b = __builtin_amdgcn_mfma_f32_16x16x32_bf16(ha, w1, p1b, 0, 0, 0);
          } else {
            aa = __builtin_amdgcn_mfma_f32_16x16x32_bf16(ha, bm, aa, 0, 0, 0);
            p0a = __builtin_amdgcn_mfma_f32_16x16x32_bf16(ha, w0, p0a, 0, 0, 0);
            p1a = __builtin_amdgcn_mfma_f32_16x16x32_bf16(ha, w1, p1a, 0, 0, 0);
          }
        }
      }
      const float wd = wd_s[cm], wl = wl_s[cm], mb = mb_s[cm];
      if (c < MCB) {
#pragma unroll
        for (int r = 0; r < 4; ++r) {
          int b_ = mt * 16 + kg * 4 + r;
          float dt = dseq[b_ * S_ + t];
          float lq = lqseq[b_ * S_ + t];
          float mval = sigm(aa[r] + ab[r] + dt * wd + lq * wl + mb);
          float xv;
          if (layer) {
            unsigned w2 = load_a4(h0r + (t & 1) * BH + b_ * H_ + mc0 + (c & ~1));
            xv = bf2f((unsigned short)((c & 1) ? (w2 >> 16) : (w2 & 0xFFFF)));
          } else {
            xv = seq[(b_ * S_ + t) * IN_ + mc0 + c];
          }
          store_short_wt(&ubuf[b_ * Kin + mc0 + c], f2bf(mval * xv));
        }
      }
    }
    gridbar(flags, epoch++);

    if (active) {
      // ---- phase 2: gates = u@Wih^T + p + bias; LSTM cell; h/out store ----
      f32x4 g0a = {0,0,0,0}, g0b = {0,0,0,0}, g1a = {0,0,0,0}, g1b = {0,0,0,0};
      const unsigned short* urow = ubuf + (mt * 16 + c) * Kin;
      const unsigned short* v0b = Wih_s + c * 1024;
      const unsigned short* v1b = Wih_s + (16 + c) * 1024;
#pragma unroll 4
      for (int kt = 0; kt < KU; ++kt) {
        short8 au = load_a16(urow + kt * 32 + kg * 8);
        int so = (((kt * 4 + kg) ^ xr) << 3);
        short8 v0 = *(const short8*)(v0b + so);
        short8 v1 = *(const short8*)(v1b + so);
        if (kt & 1) {
          g0b = __builtin_amdgcn_mfma_f32_16x16x32_bf16(au, v0, g0b, 0, 0, 0);
          g1b = __builtin_amdgcn_mfma_f32_16x16x32_bf16(au, v1, g1b, 0, 0, 0);
        } else {
          g0a = __builtin_amdgcn_mfma_f32_16x16x32_bf16(au, v0, g0a, 0, 0, 0);
          g1a = __builtin_amdgcn_mfma_f32_16x16x32_bf16(au, v1, g1a, 0, 0, 0);
        }
      }
      const float bia0 = bias_s[c], bia1 = bias_s[16 + c];
      f32x4 g0, g1, s0, s1;
#pragma unroll
      for (int r = 0; r < 4; ++r) {
        g0[r] = g0a[r] + g0b[r] + p0a[r] + p0b[r] + bia0;
        g1[r] = g1a[r] + g1b[r] + p1a[r] + p1b[r] + bia1;
      }
#pragma unroll
      for (int r = 0; r < 4; ++r) {
        s0[r] = __shfl_xor(g0[r], 8);
        s1[r] = __shfl_xor(g1[r], 8);
      }
      const bool low = c < 8;
      const int hc = hc0 + (c & 7);
      const int rbase = low ? 0 : 2;
#pragma unroll
      for (int j = 0; j < 2; ++j) {
        const int rr = rbase + j;
        float iv = low ? g0[rr] : s0[rr];
        float fv = low ? s0[rr] : g0[rr];
        float gv = low ? g1[rr] : s1[rr];
        float ov = low ? s1[rr] : g1[rr];
        float cold = j ? creg1 : creg0;
        float cn = sigm(fv) * cold + sigm(iv) * tanh_(gv);
        float hn = sigm(ov) * tanh_(cn);
        if (j) creg1 = cn; else creg0 = cn;
        int b_ = mt * 16 + kg * 4 + rr;
        store_short_wt(&myring[(t & 1) * BH + b_ * H_ + hc], f2bf(hn));
        if (layer) {
          dout[(b_ * S_ + t) * H_ + hc] = hn;
          if (t == S_ - 1) dout[B_ * S_ * H_ + b_ * H_ + hc] = hn;
        }
      }
    }
    gridbar(flags, epoch++);
  }
}

extern "C" void kernel_launch(void* const* d_in, const int* in_sizes, int n_in,
                              void* d_out, int out_size, void* d_ws,
                              size_t ws_size, hipStream_t stream) {
  char* w = (char*)d_ws;
  int* flags = (int*)w;                                          // 16 KB
  unsigned short* h0r = (unsigned short*)(w + 16384);            // 256 KB
  unsigned short* h1r = (unsigned short*)(w + 16384 + 262144);   // 256 KB
  unsigned short* u0 = (unsigned short*)(w + 16384 + 2 * 262144);          // 64 KB
  unsigned short* u1 = (unsigned short*)(w + 16384 + 2 * 262144 + 65536);  // 128 KB

  hipMemsetAsync(flags, 0, 16384, stream);

  qmog_kernel<<<NBLK, NTHR, 0, stream>>>(
      (const float*)d_in[0], (const float*)d_in[1], (const float*)d_in[2],
      (const float*)d_in[3], (const float*)d_in[4], (const float*)d_in[5],
      (const float*)d_in[6], (const float*)d_in[7], (const float*)d_in[8],
      (const float*)d_in[9], (const float*)d_in[10], (const float*)d_in[11],
      (const float*)d_in[12], (const float*)d_in[13], (const float*)d_in[14],
      (float*)d_out, flags, h0r, h1r, u0, u1);
}

// Round 4
// 10476.727 us; speedup vs baseline: 4.1775x; 1.1856x over previous
//
#include <hip/hip_runtime.h>

// QMogrifierStack: 2-layer mogrifier LSTM, B=64 S=512 IN=512 H=1024.
// Persistent cooperative kernel: 256 blocks (1/CU), blocks 0-127 = layer 0,
// 128-255 = layer 1, pipelined (layer1 one step behind layer0).
// R4: cached reads for cross-block data + ONE buffer_inv sc1 per block per
// barrier (XCD-local L2 reuse; all kernel writes are WT so L2 is never
// dirty). 512 threads = 8 waves = 2/SIMD; K split across wave pairs with
// LDS partial-sum reduction.

typedef __attribute__((ext_vector_type(8))) short short8;
typedef __attribute__((ext_vector_type(4))) float f32x4;

constexpr int B_ = 64, S_ = 512, IN_ = 512, H_ = 1024;
constexpr int NBLK = 256, NTHR = 512;
constexpr int BH = B_ * H_;

__device__ __forceinline__ unsigned short f2bf(float f) {
  unsigned u = __builtin_bit_cast(unsigned, f);
  u += 0x7FFFu + ((u >> 16) & 1u);
  return (unsigned short)(u >> 16);
}
__device__ __forceinline__ float bf2f(unsigned short h) {
  unsigned u = ((unsigned)h) << 16;
  return __builtin_bit_cast(float, u);
}
__device__ __forceinline__ float sigm(float x) { return 1.f / (1.f + __expf(-x)); }
__device__ __forceinline__ float tanh_(float x) {
  float e = __expf(2.f * x);
  return 1.f - 2.f / (e + 1.f);
}

// Write-through stores (visible at coherence point after vmcnt(0); L2 stays
// clean so barrier-exit buffer_inv never discards data).
__device__ __forceinline__ void store_short_wt(unsigned short* p, unsigned short v) {
  unsigned w = v;
  asm volatile("global_store_short %0, %1, off sc0 sc1" :: "v"(p), "v"(w) : "memory");
}
__device__ __forceinline__ void store_float_wt(float* p, float v) {
  asm volatile("global_store_dword %0, %1, off sc0 sc1" :: "v"(p), "v"(v) : "memory");
}

// flags[0..255] arrive; flags[256 + 32*i], i<8: replicated go slots.
// Exit: one buffer_inv sc1 per block drops stale clean L1/L2 lines so cached
// readers refetch fresh cross-block data; weights live in LDS, unaffected.
__device__ __forceinline__ void gridbar(int* flags, int epoch) {
  asm volatile("s_waitcnt vmcnt(0)" ::: "memory");
  __syncthreads();
  const int tid = threadIdx.x;
  if (tid == 0)
    __hip_atomic_store(&flags[blockIdx.x], epoch, __ATOMIC_RELAXED,
                       __HIP_MEMORY_SCOPE_AGENT);
  if (blockIdx.x == 0) {
    if (tid < 64) {
      bool ok;
      do {
        ok = true;
#pragma unroll
        for (int i = 0; i < 4; ++i)
          ok &= (__hip_atomic_load(&flags[tid + i * 64], __ATOMIC_RELAXED,
                                   __HIP_MEMORY_SCOPE_AGENT) >= epoch);
      } while (!__all(ok));
      if (tid < 8)
        __hip_atomic_store(&flags[256 + (tid << 5)], epoch, __ATOMIC_RELAXED,
                           __HIP_MEMORY_SCOPE_AGENT);
    }
  } else if (tid == 0) {
    while (__hip_atomic_load(&flags[256 + ((blockIdx.x & 7) << 5)],
                             __ATOMIC_RELAXED, __HIP_MEMORY_SCOPE_AGENT) < epoch) {}
  }
  if (tid == 0)
    asm volatile("buffer_inv sc1\n\ts_waitcnt vmcnt(0)" ::: "memory");
  __syncthreads();
}

__global__ __launch_bounds__(NTHR, 1) void qmog_kernel(
    const float* __restrict__ seq, const float* __restrict__ dseq,
    const float* __restrict__ lqseq,
    const float* __restrict__ modW0, const float* __restrict__ modb0,
    const float* __restrict__ Wih0, const float* __restrict__ Whh0,
    const float* __restrict__ bih0, const float* __restrict__ bhh0,
    const float* __restrict__ modW1, const float* __restrict__ modb1,
    const float* __restrict__ Wih1, const float* __restrict__ Whh1,
    const float* __restrict__ bih1, const float* __restrict__ bhh1,
    float* __restrict__ dout, int* __restrict__ flags,
    unsigned short* __restrict__ h0r, unsigned short* __restrict__ h1r,
    unsigned short* __restrict__ u0, unsigned short* __restrict__ u1) {
  __shared__ unsigned short Wih_s[32 * 1024];   // 64 KB
  __shared__ unsigned short Whh_s[32 * 1024];   // 64 KB
  __shared__ unsigned short modW_s[8 * 1024];   // 16 KB
  __shared__ float red_s[4][12][64];            // 12 KB split-K partials
  __shared__ float bias_s[32];
  __shared__ float wd_s[8], wl_s[8], mb_s[8];

  const int bid = blockIdx.x, tid = threadIdx.x;
  const int layer = bid >> 7;
  const int slice = bid & 127;
  const int wave = tid >> 6, lane = tid & 63;
  const int mt = wave & 3;            // M-tile (16 batch rows)
  const int kh = wave >> 2;           // K-half (0 or 1)
  const int Kin = layer ? H_ : IN_;   // 1024 / 512
  const int KU = Kin / 32;            // 32 / 16 k-tiles total (phase 2)
  const int MCB = layer ? 8 : 4;      // m-cols per block
  const int hc0 = slice * 8;
  const int mc0 = slice * MCB;
  const float* modW = layer ? modW1 : modW0;
  const float* modb = layer ? modb1 : modb0;
  const float* Wih  = layer ? Wih1 : Wih0;
  const float* Whh  = layer ? Whh1 : Whh0;
  const float* bih  = layer ? bih1 : bih0;
  const float* bhh  = layer ? bhh1 : bhh0;
  unsigned short* ubuf = layer ? u1 : u0;
  unsigned short* myring = layer ? h1r : h0r;

  // ---- stage weight slices f32->bf16 into LDS (pitch 1024, no swizzle:
  // compile-time ds offsets; conflict level is structural either way) ----
  // LDS row r -> global gate row (r>>3)*H + hc0 + (r&7): [i0..7,f0..7,g0..7,o0..7]
  for (int idx = tid; idx < 32 * Kin; idx += NTHR) {
    int row = idx / Kin, k = idx - row * Kin;
    int grow = (row >> 3) * H_ + hc0 + (row & 7);
    Wih_s[row * 1024 + k] = f2bf(Wih[grow * Kin + k]);
  }
  for (int idx = tid; idx < 32 * H_; idx += NTHR) {
    int row = idx >> 10, k = idx & (H_ - 1);
    int grow = (row >> 3) * H_ + hc0 + (row & 7);
    Whh_s[row * 1024 + k] = f2bf(Whh[grow * H_ + k]);
  }
  for (int idx = tid; idx < MCB * H_; idx += NTHR) {
    int row = idx >> 10, k = idx & (H_ - 1);
    modW_s[row * 1024 + k] = f2bf(modW[(mc0 + row) * (H_ + 2) + k]);
  }
  if (tid < 32) {
    int grow = (tid >> 3) * H_ + hc0 + (tid & 7);
    bias_s[tid] = bih[grow] + bhh[grow];
  }
  if (tid < MCB) {
    wd_s[tid] = modW[(mc0 + tid) * (H_ + 2) + H_];
    wl_s[tid] = modW[(mc0 + tid) * (H_ + 2) + H_ + 1];
    mb_s[tid] = modb[mc0 + tid];
  }
  __syncthreads();

  float creg0 = 0.f, creg1 = 0.f;     // cell state (kh==0 waves only)
  int epoch = 1;
  const int c = lane & 15, kg = lane >> 4;
  const int cm = c & (MCB - 1);

  for (int s = 0; s <= S_; ++s) {
    const int t = layer ? (s - 1) : s;
    const bool active = (t >= 0) && (t < S_);

    // h@Whh^T totals, carried phase1 -> phase2 (valid in kh==0 waves)
    f32x4 pm0 = {0,0,0,0}, pm1 = {0,0,0,0};

    if (active) {
      // ---- phase 1: mod-GEMM + Whh-GEMM, split-K over wave pairs ----
      f32x4 mA = {0,0,0,0}, mB = {0,0,0,0};
      if (t > 0) {
        f32x4 p0A = {0,0,0,0}, p0B = {0,0,0,0}, p1A = {0,0,0,0}, p1B = {0,0,0,0};
        const unsigned short* hrow =
            myring + ((t - 1) & 1) * BH + (mt * 16 + c) * H_ + kh * 512;
        const unsigned short* wm = modW_s + cm * 1024 + kh * 512;
        const unsigned short* w0b = Whh_s + c * 1024 + kh * 512;
        const unsigned short* w1b = Whh_s + (16 + c) * 1024 + kh * 512;
#pragma unroll
        for (int kk = 0; kk < 16; ++kk) {
          short8 ha = *(const short8*)(hrow + kk * 32 + kg * 8);
          short8 bm = *(const short8*)(wm + kk * 32 + kg * 8);
          short8 w0 = *(const short8*)(w0b + kk * 32 + kg * 8);
          short8 w1 = *(const short8*)(w1b + kk * 32 + kg * 8);
          if (kk & 1) {
            mB = __builtin_amdgcn_mfma_f32_16x16x32_bf16(ha, bm, mB, 0, 0, 0);
            p0B = __builtin_amdgcn_mfma_f32_16x16x32_bf16(ha, w0, p0B, 0, 0, 0);
            p1B = __builtin_amdgcn_mfma_f32_16x16x32_bf16(ha, w1, p1B, 0, 0, 0);
          } else {
            mA = __builtin_amdgcn_mfma_f32_16x16x32_bf16(ha, bm, mA, 0, 0, 0);
            p0A = __builtin_amdgcn_mfma_f32_16x16x32_bf16(ha, w0, p0A, 0, 0, 0);
            p1A = __builtin_amdgcn_mfma_f32_16x16x32_bf16(ha, w1, p1A, 0, 0, 0);
          }
        }
        if (kh) {
#pragma unroll
          for (int r = 0; r < 4; ++r) {
            red_s[mt][r][lane] = mA[r] + mB[r];
            red_s[mt][4 + r][lane] = p0A[r] + p0B[r];
            red_s[mt][8 + r][lane] = p1A[r] + p1B[r];
          }
        }
        __syncthreads();
        if (!kh) {
#pragma unroll
          for (int r = 0; r < 4; ++r) {
            mA[r] += mB[r] + red_s[mt][r][lane];
            pm0[r] = p0A[r] + p0B[r] + red_s[mt][4 + r][lane];
            pm1[r] = p1A[r] + p1B[r] + red_s[mt][8 + r][lane];
          }
        }
      }
      if (!kh && c < MCB) {
        const float wd = wd_s[cm], wl = wl_s[cm], mb = mb_s[cm];
#pragma unroll
        for (int r = 0; r < 4; ++r) {
          int b_ = mt * 16 + kg * 4 + r;
          float dt = dseq[b_ * S_ + t];
          float lq = lqseq[b_ * S_ + t];
          float mval = sigm(mA[r] + dt * wd + lq * wl + mb);
          float xv = layer ? bf2f(h0r[(t & 1) * BH + b_ * H_ + mc0 + c])
                           : seq[(b_ * S_ + t) * IN_ + mc0 + c];
          store_short_wt(&ubuf[b_ * Kin + mc0 + c], f2bf(mval * xv));
        }
      }
    }
    gridbar(flags, epoch++);

    if (active) {
      // ---- phase 2: u@Wih^T split-K; combine + cell in kh==0 waves ----
      f32x4 g0A = {0,0,0,0}, g0B = {0,0,0,0}, g1A = {0,0,0,0}, g1B = {0,0,0,0};
      const int ku2 = KU >> 1;        // 16 (L1) or 8 (L0) k-tiles per wave
      const unsigned short* urow = ubuf + (mt * 16 + c) * Kin + kh * (ku2 * 32);
      const unsigned short* v0b = Wih_s + c * 1024 + kh * (ku2 * 32);
      const unsigned short* v1b = Wih_s + (16 + c) * 1024 + kh * (ku2 * 32);
#pragma unroll
      for (int kk = 0; kk < 16; ++kk) {
        if (kk < ku2) {
          short8 au = *(const short8*)(urow + kk * 32 + kg * 8);
          short8 v0 = *(const short8*)(v0b + kk * 32 + kg * 8);
          short8 v1 = *(const short8*)(v1b + kk * 32 + kg * 8);
          if (kk & 1) {
            g0B = __builtin_amdgcn_mfma_f32_16x16x32_bf16(au, v0, g0B, 0, 0, 0);
            g1B = __builtin_amdgcn_mfma_f32_16x16x32_bf16(au, v1, g1B, 0, 0, 0);
          } else {
            g0A = __builtin_amdgcn_mfma_f32_16x16x32_bf16(au, v0, g0A, 0, 0, 0);
            g1A = __builtin_amdgcn_mfma_f32_16x16x32_bf16(au, v1, g1A, 0, 0, 0);
          }
        }
      }
      if (kh) {
#pragma unroll
        for (int r = 0; r < 4; ++r) {
          red_s[mt][r][lane] = g0A[r] + g0B[r];
          red_s[mt][4 + r][lane] = g1A[r] + g1B[r];
        }
      }
      __syncthreads();
      if (!kh) {
        const float bia0 = bias_s[c], bia1 = bias_s[16 + c];
        f32x4 g0, g1, s0, s1;
#pragma unroll
        for (int r = 0; r < 4; ++r) {
          g0[r] = g0A[r] + g0B[r] + red_s[mt][r][lane] + pm0[r] + bia0;
          g1[r] = g1A[r] + g1B[r] + red_s[mt][4 + r][lane] + pm1[r] + bia1;
        }
#pragma unroll
        for (int r = 0; r < 4; ++r) {
          s0[r] = __shfl_xor(g0[r], 8);
          s1[r] = __shfl_xor(g1[r], 8);
        }
        // Lane c<8 holds i (tile0) / g (tile1); c>=8 holds f / o. After xor-8
        // all four present; low lanes take rows 0,1, high lanes rows 2,3.
        const bool low = c < 8;
        const int hc = hc0 + (c & 7);
        const int rbase = low ? 0 : 2;
#pragma unroll
        for (int j = 0; j < 2; ++j) {
          const int rr = rbase + j;
          float iv = low ? g0[rr] : s0[rr];
          float fv = low ? s0[rr] : g0[rr];
          float gv = low ? g1[rr] : s1[rr];
          float ov = low ? s1[rr] : g1[rr];
          float cold = j ? creg1 : creg0;
          float cn = sigm(fv) * cold + sigm(iv) * tanh_(gv);
          float hn = sigm(ov) * tanh_(cn);
          if (j) creg1 = cn; else creg0 = cn;
          int b_ = mt * 16 + kg * 4 + rr;
          store_short_wt(&myring[(t & 1) * BH + b_ * H_ + hc], f2bf(hn));
          if (layer) {
            store_float_wt(&dout[(b_ * S_ + t) * H_ + hc], hn);
            if (t == S_ - 1) store_float_wt(&dout[B_ * S_ * H_ + b_ * H_ + hc], hn);
          }
        }
      }
    }
    gridbar(flags, epoch++);
  }
}

extern "C" void kernel_launch(void* const* d_in, const int* in_sizes, int n_in,
                              void* d_out, int out_size, void* d_ws,
                              size_t ws_size, hipStream_t stream) {
  char* w = (char*)d_ws;
  int* flags = (int*)w;                                          // 16 KB
  unsigned short* h0r = (unsigned short*)(w + 16384);            // 256 KB
  unsigned short* h1r = (unsigned short*)(w + 16384 + 262144);   // 256 KB
  unsigned short* u0 = (unsigned short*)(w + 16384 + 2 * 262144);          // 64 KB
  unsigned short* u1 = (unsigned short*)(w + 16384 + 2 * 262144 + 65536);  // 128 KB

  hipMemsetAsync(flags, 0, 16384, stream);

  qmog_kernel<<<NBLK, NTHR, 0, stream>>>(
      (const float*)d_in[0], (const float*)d_in[1], (const float*)d_in[2],
      (const float*)d_in[3], (const float*)d_in[4], (const float*)d_in[5],
      (const float*)d_in[6], (const float*)d_in[7], (const float*)d_in[8],
      (const float*)d_in[9], (const float*)d_in[10], (const float*)d_in[11],
      (const float*)d_in[12], (const float*)d_in[13], (const float*)d_in[14],
      (float*)d_out, flags, h0r, h1r, u0, u1);
}